// Round 1
// baseline (57.168 us; speedup 1.0000x reference)
//
#include <hip/hip_runtime.h>

#define D    256
#define KCB  2048
#define HW   1024
#define BN   64

typedef __attribute__((ext_vector_type(8))) short bf16x8;
typedef __attribute__((ext_vector_type(4))) float f32x4;

__device__ __forceinline__ unsigned short f2bf(float f) {
  union { float f; unsigned u; } v; v.f = f;
  unsigned r = v.u + 0x7fffu + ((v.u >> 16) & 1u);   // RTNE
  return (unsigned short)(r >> 16);
}

// K1: codebook fp32 -> bf16 (row-major 2048x256) + cnorm[row] = ||c||^2
__global__ __launch_bounds__(256) void vq_prep(const float* __restrict__ cb,
                                               unsigned short* __restrict__ cbh,
                                               float* __restrict__ cnorm) {
  int row = blockIdx.x;
  int t = threadIdx.x;
  float c = cb[(size_t)row * D + t];
  cbh[(size_t)row * D + t] = f2bf(c);
  float s = c * c;
#pragma unroll
  for (int off = 32; off; off >>= 1) s += __shfl_down(s, off, 64);
  __shared__ float ws4[4];
  if ((t & 63) == 0) ws4[t >> 6] = s;
  __syncthreads();
  if (t == 0) cnorm[row] = (ws4[0] + ws4[1]) + (ws4[2] + ws4[3]);
}

// K2: fused distance-GEMM (bf16 MFMA) + argmin + gather + commitment partials.
// One block per 64 output columns: grid = 16 batches * 16 column-tiles = 256.
__global__ __launch_bounds__(256, 1) void vq_main(
    const float* __restrict__ z, const float* __restrict__ cb,
    const unsigned short* __restrict__ cbh, const float* __restrict__ cnorm,
    float* __restrict__ qout, float* __restrict__ partial) {
  __shared__ char smem[65536];
  char* ZT = smem;           // [64 cols][256 k] bf16, XOR-swizzled (32 KB)
  char* As = smem + 32768;   // [256 rows][64 k] bf16, XOR-swizzled (32 KB)

  const int t = threadIdx.x;
  const int l = t & 63;     // lane
  const int w = t >> 6;     // wave (4)
  const int g = l >> 4;     // lane group
  const int cl = l & 15;
  const int b = blockIdx.x >> 4;
  const int m0 = (blockIdx.x & 15) * BN;
  const float* zb = z + (size_t)b * (D * HW) + m0;

  // ---- stage ZT = bf16(-2*z), transposed (col-major rows) + swizzled ----
  // thread: column mm = l, wave w covers d === {2w, 2w+1} mod 8
#pragma unroll 4
  for (int it = 0; it < 32; ++it) {
    int d0 = it * 8 + w * 2;
    float v0 = zb[(size_t)d0 * HW + l];
    float v1 = zb[(size_t)(d0 + 1) * HW + l];
    unsigned pk = (unsigned)f2bf(-2.f * v0) | ((unsigned)f2bf(-2.f * v1) << 16);
    *(unsigned*)(ZT + l * 512 + ((d0 * 2) ^ ((l & 7) << 4))) = pk;
  }

  float bestv[4]; int bestk[4];
#pragma unroll
  for (int cf = 0; cf < 4; ++cf) { bestv[cf] = 3.4e38f; bestk[cf] = 0; }

  // ---- M-loop over codebook rows, 256 per tile ----
  for (int mt = 0; mt < 8; ++mt) {
    f32x4 acc[4][4];
#pragma unroll
    for (int mf = 0; mf < 4; ++mf)
#pragma unroll
      for (int cf = 0; cf < 4; ++cf) acc[mf][cf] = (f32x4){0.f, 0.f, 0.f, 0.f};

    for (int kt = 0; kt < 4; ++kt) {
      __syncthreads();   // previous A-chunk reads complete
      // stage A chunk: rows [mt*256,+256) x k [kt*64,+64), 16B/lane,
      // linear LDS dest; swizzle applied by permuting the GLOBAL source k-slot.
#pragma unroll
      for (int i = 0; i < 8; ++i) {
        int r = w * 64 + i * 8 + (l >> 3);
        int kg = (l & 7) ^ (r & 7);
        const unsigned short* gp =
            cbh + (size_t)(mt * 256 + r) * D + kt * 64 + kg * 8;
        __builtin_amdgcn_global_load_lds(
            (const __attribute__((address_space(1))) void*)gp,
            (__attribute__((address_space(3))) void*)(As + w * 8192 + i * 1024),
            16, 0, 0);
      }
      __syncthreads();   // staged data visible (vmcnt drained by barrier)

#pragma unroll
      for (int ks = 0; ks < 2; ++ks) {
        bf16x8 af[4], bv[4];
#pragma unroll
        for (int mf = 0; mf < 4; ++mf) {
          int r = w * 64 + mf * 16 + cl;
          af[mf] = *(const bf16x8*)(As + r * 128 +
                                    ((ks * 64 + g * 16) ^ ((r & 7) << 4)));
        }
        int kbyte = kt * 128 + ks * 64 + g * 16;
#pragma unroll
        for (int cf = 0; cf < 4; ++cf) {
          int c = cf * 16 + cl;
          bv[cf] = *(const bf16x8*)(ZT + c * 512 + (kbyte ^ ((cl & 7) << 4)));
        }
#pragma unroll
        for (int mf = 0; mf < 4; ++mf)
#pragma unroll
          for (int cf = 0; cf < 4; ++cf)
            acc[mf][cf] = __builtin_amdgcn_mfma_f32_16x16x32_bf16(
                af[mf], bv[cf], acc[mf][cf], 0, 0, 0);
      }
    }

    // ---- argmin update: dist = ||c||^2 + (-2 z . c) ----
#pragma unroll
    for (int mf = 0; mf < 4; ++mf) {
#pragma unroll
      for (int i = 0; i < 4; ++i) {
        int row = mt * 256 + w * 64 + mf * 16 + g * 4 + i;   // C/D row map (m89)
        float cn = cnorm[row];
#pragma unroll
        for (int cf = 0; cf < 4; ++cf) {
          float v = cn + acc[mf][cf][i];
          if (v < bestv[cf]) { bestv[cf] = v; bestk[cf] = row; }
        }
      }
    }
  }

  __syncthreads();   // all LDS tile reads done; reuse smem for reductions
  float* redv = (float*)smem;            // [4 waves][4 cf][16]
  int* redk = (int*)(smem + 1024);
  int* kbest_s = (int*)(smem + 2048);    // [64]
  float* wsum = (float*)(smem + 2304);   // [4]

#pragma unroll
  for (int cf = 0; cf < 4; ++cf) {
    float v = bestv[cf]; int kk = bestk[cf];
#pragma unroll
    for (int off = 16; off < 64; off <<= 1) {
      float ov = __shfl_xor(v, off, 64);
      int ok = __shfl_xor(kk, off, 64);
      if (ov < v || (ov == v && ok < kk)) { v = ov; kk = ok; }
    }
    if (g == 0) { redv[(w * 4 + cf) * 16 + cl] = v; redk[(w * 4 + cf) * 16 + cl] = kk; }
  }
  __syncthreads();
  if (t < 64) {
    int cf = t >> 4, c2 = t & 15;
    float v = redv[cf * 16 + c2]; int kk = redk[cf * 16 + c2];
#pragma unroll
    for (int w2 = 1; w2 < 4; ++w2) {
      float ov = redv[(w2 * 4 + cf) * 16 + c2];
      int ok = redk[(w2 * 4 + cf) * 16 + c2];
      if (ov < v || (ov == v && ok < kk)) { v = ov; kk = ok; }
    }
    kbest_s[cf * 16 + c2] = kk;
  }
  __syncthreads();

  // ---- output q (exact fp32 codebook gather) + commitment partial ----
  {
    int mm = l;                 // column within block (coalesced stores)
    int dbase = w * 64;         // each wave owns a d-quarter
    int krow = kbest_s[mm];
    const float* crow = cb + (size_t)krow * D + dbase;
    const float* zcol = zb + (size_t)dbase * HW + mm;
    float* qcol = qout + (size_t)b * (D * HW) + m0 + (size_t)dbase * HW + mm;
    float sum = 0.f;
#pragma unroll 4
    for (int i4 = 0; i4 < 16; ++i4) {
      float4 cv4 = *(const float4*)(crow + i4 * 4);
      const float* cva = (const float*)&cv4;
#pragma unroll
      for (int j = 0; j < 4; ++j) {
        int d = i4 * 4 + j;
        float zv = zcol[(size_t)d * HW];
        float df = zv - cva[j];
        sum += df * df;
        qcol[(size_t)d * HW] = cva[j];
      }
    }
#pragma unroll
    for (int off = 32; off; off >>= 1) sum += __shfl_down(sum, off, 64);
    if (l == 0) wsum[w] = sum;
  }
  __syncthreads();
  if (t == 0) partial[blockIdx.x] = (wsum[0] + wsum[1]) + (wsum[2] + wsum[3]);
}

// K3: deterministic reduction of 256 block partials -> loss scalars
__global__ __launch_bounds__(256) void vq_finalize(const float* __restrict__ partial,
                                                   float* __restrict__ out) {
  int t = threadIdx.x;
  float s = partial[t];
#pragma unroll
  for (int off = 32; off; off >>= 1) s += __shfl_down(s, off, 64);
  __shared__ float ws4[4];
  if ((t & 63) == 0) ws4[t >> 6] = s;
  __syncthreads();
  if (t == 0) {
    float tot = (ws4[0] + ws4[1]) + (ws4[2] + ws4[3]);
    float commit = tot / 4194304.0f;
    out[4194304] = 0.25f * commit;
    out[4194305] = commit;
  }
}

extern "C" void kernel_launch(void* const* d_in, const int* in_sizes, int n_in,
                              void* d_out, int out_size, void* d_ws, size_t ws_size,
                              hipStream_t stream) {
  const float* z = (const float*)d_in[0];
  const float* cb = (const float*)d_in[1];
  float* out = (float*)d_out;
  unsigned short* cbh = (unsigned short*)d_ws;                        // 1 MB
  float* cnorm = (float*)((char*)d_ws + (size_t)KCB * D * 2);         // 8 KB
  float* partial = (float*)((char*)d_ws + (size_t)KCB * D * 2 + KCB * 4);  // 1 KB

  vq_prep<<<KCB, 256, 0, stream>>>(cb, cbh, cnorm);
  vq_main<<<256, 256, 0, stream>>>(z, cb, cbh, cnorm, out, partial);
  vq_finalize<<<1, 256, 0, stream>>>(partial, out);
}

// Round 2
// 40.626 us; speedup vs baseline: 1.4072x; 1.4072x over previous
//
#include <hip/hip_runtime.h>

#define D    256
#define KCB  2048
#define HW   1024
#define BN   64

typedef __attribute__((ext_vector_type(8))) short bf16x8;
typedef __attribute__((ext_vector_type(4))) float f32x4;

__device__ __forceinline__ unsigned short f2bf(float f) {
  union { float f; unsigned u; } v; v.f = f;
  unsigned r = v.u + 0x7fffu + ((v.u >> 16) & 1u);   // RTNE
  return (unsigned short)(r >> 16);
}

// K1: codebook fp32 -> bf16 (row-major 2048x256) + cnorm[row] = ||c||^2
__global__ __launch_bounds__(256) void vq_prep(const float* __restrict__ cb,
                                               unsigned short* __restrict__ cbh,
                                               float* __restrict__ cnorm) {
  int row = blockIdx.x;
  int t = threadIdx.x;
  float c = cb[(size_t)row * D + t];
  cbh[(size_t)row * D + t] = f2bf(c);
  float s = c * c;
#pragma unroll
  for (int off = 32; off; off >>= 1) s += __shfl_down(s, off, 64);
  __shared__ float ws4[4];
  if ((t & 63) == 0) ws4[t >> 6] = s;
  __syncthreads();
  if (t == 0) cnorm[row] = (ws4[0] + ws4[1]) + (ws4[2] + ws4[3]);
}

__device__ __forceinline__ void stage_chunk(const unsigned short* __restrict__ cbh,
                                            int rowbase, int mt, int kt,
                                            char* dst, int w, int l) {
  // chunk = 128 rows x 64 k, linear LDS dest, k-slot pre-swizzled on global src
#pragma unroll
  for (int i = 0; i < 4; ++i) {
    int r = w * 32 + i * 8 + (l >> 3);
    int kg = (l & 7) ^ (r & 7);
    const unsigned short* gp =
        cbh + (((size_t)(rowbase + mt * 128 + r)) << 8) + kt * 64 + kg * 8;
    __builtin_amdgcn_global_load_lds(
        (const __attribute__((address_space(1))) void*)gp,
        (__attribute__((address_space(3))) void*)(dst + w * 4096 + i * 1024 + l * 16),
        16, 0, 0);
  }
}

// K2: half-codebook distance GEMM. grid = 256 coltiles x 2 halves = 512.
// B (z-tile) cached entirely in registers; LDS = double-buffered A chunks.
__global__ __launch_bounds__(256, 2) void vq_main(
    const float* __restrict__ z, const unsigned short* __restrict__ cbh,
    const float* __restrict__ cnorm,
    float* __restrict__ bestv_ws, int* __restrict__ bestk_ws,
    float* __restrict__ zsq_ws) {
  __shared__ __align__(16) char smem[38400];
  char* const bufs[2] = { smem, smem + 16384 };        // A dbuf 2x16KB
  char* ZT = smem;                                      // [64 cols][256 k] bf16 (prologue only)
  float* cnorm_s = (float*)(smem + 32768);              // 1024 f32
  float* zred = (float*)(smem + 36864);                 // 256 f32

  const int t = threadIdx.x;
  const int l = t & 63, w = t >> 6, g = l >> 4, cl = l & 15;
  const int bid = blockIdx.x;
  const int ct = bid >> 1, hf = bid & 1;
  const int b = ct >> 4, m0 = (ct & 15) * BN;
  const int rowbase = hf * 1024;
  const float* zb = z + (size_t)b * (D * HW) + m0;

  // ---- prologue: stage ZT = bf16(-2z) transposed+swizzled; zsq partials ----
  float zp = 0.f;
#pragma unroll 4
  for (int it = 0; it < 32; ++it) {
    int d0 = it * 8 + w * 2;
    float v0 = zb[(size_t)d0 * HW + l];
    float v1 = zb[(size_t)(d0 + 1) * HW + l];
    zp += v0 * v0 + v1 * v1;
    unsigned pk = (unsigned)f2bf(-2.f * v0) | ((unsigned)f2bf(-2.f * v1) << 16);
    *(unsigned*)(ZT + l * 512 + ((d0 * 2) ^ ((l & 7) << 4))) = pk;
  }
  zred[t] = zp;
#pragma unroll
  for (int i = 0; i < 4; ++i) cnorm_s[t + i * 256] = cnorm[rowbase + t + i * 256];
  __syncthreads();
  if (t < 64)
    zsq_ws[ct * 64 + t] = (zred[t] + zred[t + 64]) + (zred[t + 128] + zred[t + 192]);

  // ---- load ALL B fragments to registers (shared by all waves) ----
  bf16x8 bvc[4][8];
#pragma unroll
  for (int s = 0; s < 8; ++s)
#pragma unroll
    for (int cf = 0; cf < 4; ++cf) {
      int c = cf * 16 + cl;
      bvc[cf][s] = *(const bf16x8*)(ZT + c * 512 + ((s * 64 + g * 16) ^ ((c & 7) << 4)));
    }
  __syncthreads();   // ZT reads done; its LDS becomes the A double-buffer

  float bestvr[4]; int bestkr[4];
#pragma unroll
  for (int cf = 0; cf < 4; ++cf) { bestvr[cf] = 3.4e38f; bestkr[cf] = 0; }

  stage_chunk(cbh, rowbase, 0, 0, bufs[0], w, l);   // prologue stage (4 glds in flight)

  for (int mt = 0; mt < 8; ++mt) {
    f32x4 acc[2][4];
#pragma unroll
    for (int mf = 0; mf < 2; ++mf)
#pragma unroll
      for (int cf = 0; cf < 4; ++cf) acc[mf][cf] = (f32x4){0.f, 0.f, 0.f, 0.f};

#pragma unroll
    for (int kt = 0; kt < 4; ++kt) {
      if (!(mt == 7 && kt == 3)) {
        int nmt = (kt == 3) ? mt + 1 : mt;
        int nkt = (kt + 1) & 3;
        stage_chunk(cbh, rowbase, nmt, nkt, bufs[(kt + 1) & 1], w, l);
        asm volatile("s_waitcnt vmcnt(4)" ::: "memory");   // cur chunk done, next in flight
      } else {
        asm volatile("s_waitcnt vmcnt(0)" ::: "memory");
      }
      __builtin_amdgcn_s_barrier();
      const char* Ac = bufs[kt & 1];
#pragma unroll
      for (int ks = 0; ks < 2; ++ks) {
        bf16x8 af[2];
#pragma unroll
        for (int mf = 0; mf < 2; ++mf) {
          int r = w * 32 + mf * 16 + cl;
          af[mf] = *(const bf16x8*)(Ac + r * 128 + ((ks * 64 + g * 16) ^ ((r & 7) << 4)));
        }
#pragma unroll
        for (int mf = 0; mf < 2; ++mf)
#pragma unroll
          for (int cf = 0; cf < 4; ++cf)
            acc[mf][cf] = __builtin_amdgcn_mfma_f32_16x16x32_bf16(
                af[mf], bvc[cf][kt * 2 + ks], acc[mf][cf], 0, 0, 0);
      }
      __builtin_amdgcn_s_barrier();   // all reads of this buffer done before re-stage
    }

    // ---- argmin update for this 128-row tile (LDS cnorm only: no VMEM) ----
#pragma unroll
    for (int mf = 0; mf < 2; ++mf)
#pragma unroll
      for (int i = 0; i < 4; ++i) {
        int lr = mt * 128 + w * 32 + mf * 16 + g * 4 + i;   // C/D row map (m89)
        float cn = cnorm_s[lr];
        int grow = rowbase + lr;
#pragma unroll
        for (int cf = 0; cf < 4; ++cf) {
          float v = cn + acc[mf][cf][i];
          if (v < bestvr[cf]) { bestvr[cf] = v; bestkr[cf] = grow; }
        }
      }
  }

  // ---- reduce argmin across lanes/waves; write per-half results ----
  __syncthreads();
  float* redv = (float*)smem;            // [4 waves][4 cf][16]
  int* redk = (int*)(smem + 1024);
#pragma unroll
  for (int cf = 0; cf < 4; ++cf) {
    float v = bestvr[cf]; int kk = bestkr[cf];
#pragma unroll
    for (int off = 16; off < 64; off <<= 1) {
      float ov = __shfl_xor(v, off, 64);
      int ok = __shfl_xor(kk, off, 64);
      if (ov < v || (ov == v && ok < kk)) { v = ov; kk = ok; }
    }
    if (g == 0) { redv[(w * 4 + cf) * 16 + cl] = v; redk[(w * 4 + cf) * 16 + cl] = kk; }
  }
  __syncthreads();
  if (t < 64) {
    int cf = t >> 4, c2 = t & 15;
    float v = redv[cf * 16 + c2]; int kk = redk[cf * 16 + c2];
#pragma unroll
    for (int w2 = 1; w2 < 4; ++w2) {
      float ov = redv[(w2 * 4 + cf) * 16 + c2];
      int ok = redk[(w2 * 4 + cf) * 16 + c2];
      if (ov < v || (ov == v && ok < kk)) { v = ov; kk = ok; }
    }
    bestv_ws[bid * 64 + t] = v;
    bestk_ws[bid * 64 + t] = kk;
  }
}

// K3: merge halves, gather q (exact fp32 codebook), commitment partial per coltile
__global__ __launch_bounds__(256) void vq_epilogue(
    const float* __restrict__ cb, const float* __restrict__ bestv_ws,
    const int* __restrict__ bestk_ws, const float* __restrict__ zsq_ws,
    float* __restrict__ qout, float* __restrict__ partial) {
  __shared__ int kbest_s[64];
  const int t = threadIdx.x, l = t & 63, w = t >> 6;
  const int ct = blockIdx.x;
  const int b = ct >> 4, m0 = (ct & 15) * BN;
  if (t < 64) {
    float v0 = bestv_ws[(ct * 2 + 0) * 64 + t]; int k0 = bestk_ws[(ct * 2 + 0) * 64 + t];
    float v1 = bestv_ws[(ct * 2 + 1) * 64 + t]; int k1 = bestk_ws[(ct * 2 + 1) * 64 + t];
    int kk = (v1 < v0) ? k1 : k0;
    float vv = (v1 < v0) ? v1 : v0;
    kbest_s[t] = kk;
    float cpart = zsq_ws[ct * 64 + t] + vv;    // sum_d (z-c)^2 for this column
#pragma unroll
    for (int off = 32; off; off >>= 1) cpart += __shfl_down(cpart, off, 64);
    if (t == 0) partial[ct] = cpart;
  }
  __syncthreads();
  int krow = kbest_s[l];
  const float* crow = cb + (size_t)krow * D + w * 64;
  float* qcol = qout + (size_t)b * (D * HW) + m0 + (size_t)(w * 64) * HW + l;
#pragma unroll 4
  for (int i4 = 0; i4 < 16; ++i4) {
    float4 cv = *(const float4*)(crow + i4 * 4);
    qcol[(size_t)(i4 * 4 + 0) * HW] = cv.x;
    qcol[(size_t)(i4 * 4 + 1) * HW] = cv.y;
    qcol[(size_t)(i4 * 4 + 2) * HW] = cv.z;
    qcol[(size_t)(i4 * 4 + 3) * HW] = cv.w;
  }
}

// K4: deterministic reduction of 256 coltile partials -> loss scalars
__global__ __launch_bounds__(256) void vq_finalize(const float* __restrict__ partial,
                                                   float* __restrict__ out) {
  int t = threadIdx.x;
  float s = partial[t];
#pragma unroll
  for (int off = 32; off; off >>= 1) s += __shfl_down(s, off, 64);
  __shared__ float ws4[4];
  if ((t & 63) == 0) ws4[t >> 6] = s;
  __syncthreads();
  if (t == 0) {
    float tot = (ws4[0] + ws4[1]) + (ws4[2] + ws4[3]);
    float commit = tot / 4194304.0f;
    out[4194304] = 0.25f * commit;
    out[4194305] = commit;
  }
}

extern "C" void kernel_launch(void* const* d_in, const int* in_sizes, int n_in,
                              void* d_out, int out_size, void* d_ws, size_t ws_size,
                              hipStream_t stream) {
  const float* z = (const float*)d_in[0];
  const float* cb = (const float*)d_in[1];
  float* out = (float*)d_out;
  char* ws = (char*)d_ws;
  unsigned short* cbh = (unsigned short*)ws;                       // 1 MB
  float* cnorm   = (float*)(ws + 1048576);                         // 8 KB
  float* partial = (float*)(ws + 1056768);                         // 1 KB
  float* bestv_ws = (float*)(ws + 1057792);                        // 128 KB
  int*   bestk_ws = (int*)(ws + 1188864);                          // 128 KB
  float* zsq_ws   = (float*)(ws + 1319936);                        // 64 KB

  vq_prep<<<KCB, 256, 0, stream>>>(cb, cbh, cnorm);
  vq_main<<<512, 256, 0, stream>>>(z, cbh, cnorm, bestv_ws, bestk_ws, zsq_ws);
  vq_epilogue<<<256, 256, 0, stream>>>(cb, bestv_ws, bestk_ws, zsq_ws, out, partial);
  vq_finalize<<<1, 256, 0, stream>>>(partial, out);
}